// Round 9
// baseline (1289.909 us; speedup 1.0000x reference)
//
#include <hip/hip_runtime.h>
#include <stdint.h>

#define AS1C(p) ((const __attribute__((address_space(1))) void*)(p))
#define AS3(p)  ((__attribute__((address_space(3))) void*)(p))

typedef short bf16x8 __attribute__((ext_vector_type(8)));
typedef float f32x4  __attribute__((ext_vector_type(4)));
typedef unsigned short u16x8 __attribute__((ext_vector_type(8)));

static __device__ __forceinline__ unsigned pack_bf16_2(float lo, float hi) {
  return (__float_as_uint(lo) >> 16) | (__float_as_uint(hi) & 0xFFFF0000u);
}
static __device__ __forceinline__ unsigned short bf16_rnd(float v) {
  return (unsigned short)((__float_as_uint(v) + 0x8000u) >> 16);
}
static __device__ __forceinline__ float bf16_f(unsigned short u) {
  return __uint_as_float(((unsigned)u) << 16);
}

// ---------------- fp32 -> bf16 convert, both inputs in one launch ------------
__global__ __launch_bounds__(256) void cvt2_f32_bf16(const float* __restrict__ inS,
                                                     uint2* __restrict__ outS,
                                                     long long n4s,
                                                     const float* __restrict__ inT,
                                                     uint2* __restrict__ outT,
                                                     long long n4t) {
  long long i = (long long)blockIdx.x * blockDim.x + threadIdx.x;
  long long stride = (long long)gridDim.x * blockDim.x;
  const long long tot = n4s + n4t;
  for (; i < tot; i += stride) {
    const float4* src; uint2* dst; long long j;
    if (i < n4s) { src = (const float4*)inS; dst = outS; j = i; }
    else         { src = (const float4*)inT; dst = outT; j = i - n4s; }
    float4 v = src[j];
    uint2 o;
    o.x = pack_bf16_2(v.x, v.y);
    o.y = pack_bf16_2(v.z, v.w);
    dst[j] = o;
  }
}

// ---------------- 256x256 8-phase GEMM (R5 schedule), INTERLEAVED dual -------
// job = blockIdx&1 (0 = teacher, 1 = student): even per-CU work mix, no
// teacher-only fill followed by an imbalanced tail.
//   phase a: ds_read A0+B01 (12 b128, +lgkm throttle); stage2 A0(t+1) | MFMA q(0,0)
//   phase b: ds_read B23;    stage2 A1(t+1)                           | MFMA q(0,2)
//   phase c: ds_read A1;     writeB(t+1)h0; loadB(t+2)h0              | MFMA q(4,2)
//   phase d:                 writeB(t+1)h1; loadB(t+2)h1              | MFMA q(4,0)
//   boundary: s_waitcnt vmcnt(8) lgkmcnt(0)  (8 B-f4s stay in flight)

static __device__ __forceinline__ void stage2(const short* __restrict__ G, int K,
                                              int grow0, int k0,
                                              short* lds, int tid) {
  const int rl = tid >> 3;
  const int ks = ((tid & 7) ^ (rl & 7)) << 3;    // pre-swizzled source k
  const short* src = G + (size_t)(grow0 + rl) * K + k0 + ks;
  short* dst = lds + (tid >> 6) * 512;
  __builtin_amdgcn_global_load_lds(AS1C(src), AS3(dst), 16, 0, 0);
  __builtin_amdgcn_global_load_lds(AS1C(src + (size_t)64 * K), AS3(dst + 4096), 16, 0, 0);
}

static __device__ __forceinline__ void loadB(const float* __restrict__ B, int K,
                                             int grow0, int k0, int tid, float4* r) {
  const int row = tid >> 2;
  const int kb = (tid & 3) << 4;
  const float* s = B + (size_t)(grow0 + row) * K + k0 + kb;
  r[0] = *(const float4*)(s);
  r[1] = *(const float4*)(s + 4);
  r[2] = *(const float4*)(s + 8);
  r[3] = *(const float4*)(s + 12);
}

static __device__ __forceinline__ void writeB(short* buf, int tid, const float4* r) {
  const int row = tid >> 2;
  const int g0 = (tid & 3) << 1;
  uint4 w0, w1;
  w0.x = pack_bf16_2(r[0].x, r[0].y); w0.y = pack_bf16_2(r[0].z, r[0].w);
  w0.z = pack_bf16_2(r[1].x, r[1].y); w0.w = pack_bf16_2(r[1].z, r[1].w);
  w1.x = pack_bf16_2(r[2].x, r[2].y); w1.y = pack_bf16_2(r[2].z, r[2].w);
  w1.z = pack_bf16_2(r[3].x, r[3].y); w1.w = pack_bf16_2(r[3].z, r[3].w);
  const int x = (row & 7) << 3;
  *(uint4*)(buf + row * 64 + ((g0 * 8) ^ x))       = w0;
  *(uint4*)(buf + row * 64 + (((g0 + 1) * 8) ^ x)) = w1;
}

#define MFMA16(IM0, JN0)                                                        \
  __builtin_amdgcn_s_setprio(1);                                                \
  _Pragma("unroll")                                                             \
  for (int mi = 0; mi < 4; ++mi) {                                              \
    _Pragma("unroll")                                                           \
    for (int nj = 0; nj < 2; ++nj) {                                            \
      acc[(IM0) + mi][(JN0) + nj] = __builtin_amdgcn_mfma_f32_16x16x32_bf16(    \
          a_[mi][0], b_[(JN0) + nj][0], acc[(IM0) + mi][(JN0) + nj], 0, 0, 0);  \
      acc[(IM0) + mi][(JN0) + nj] = __builtin_amdgcn_mfma_f32_16x16x32_bf16(    \
          a_[mi][1], b_[(JN0) + nj][1], acc[(IM0) + mi][(JN0) + nj], 0, 0, 0);  \
    }                                                                           \
  }                                                                             \
  __builtin_amdgcn_s_setprio(0);

__global__ __launch_bounds__(512, 2) void gemm_dual(
    const short* __restrict__ A0v, const float* __restrict__ B0v,
    unsigned short* __restrict__ C0v, int K0, int NT0,
    const short* __restrict__ A1v, const float* __restrict__ B1v,
    unsigned short* __restrict__ C1v, int K1, int NT1,
    int N, int mshift, int halfGrid) {
  __shared__ __align__(16) short sA[4 * 8192];
  __shared__ __align__(16) short sB[4 * 8192];

  const int tid = threadIdx.x;
  const int lane = tid & 63;
  const int wv = tid >> 6;
  const int wm = wv >> 2;
  const int wn = wv & 3;

  // interleaved job assignment (block-uniform): even T/S mix across the run
  const bool second = (blockIdx.x & 1) != 0;
  const short* A = second ? A1v : A0v;
  const float* B = second ? B1v : B0v;
  unsigned short* C = second ? C1v : C0v;
  const int K  = second ? K1  : K0;
  const int NT = second ? NT1 : NT0;
  const int orig = (int)blockIdx.x >> 1;

  // bijective XCD-aware swizzle within each job (nwg = halfGrid)
  const int nwg = halfGrid;
  const int q = nwg >> 3, r = nwg & 7;
  const int xcd = orig & 7;
  const int wg = (xcd < r ? xcd * (q + 1) : r * (q + 1) + (xcd - r) * q) + (orig >> 3);
  const int bm = wg & ((1 << mshift) - 1);
  const int bn = wg >> mshift;

  const int mrow0 = bm << 8;
  const int nrow0 = bn << 8;

  const int lr = lane & 15;
  const int koff0 = (((lane >> 4) << 3) ^ ((lane & 7) << 3));
  const int koff1 = ((32 + ((lane >> 4) << 3)) ^ ((lane & 7) << 3));

  f32x4 acc[8][4] = {};
  bf16x8 a_[4][2], b_[4][2];
  float4 rB0[4], rB1[4];

  // ---- prologue: A(0) glds; B(0) regs->LDS; B(1) -> regs (8 f4 in flight)
  stage2(A, K, mrow0,       0, sA + 0 * 8192, tid);
  stage2(A, K, mrow0 + 128, 0, sA + 1 * 8192, tid);
  loadB(B, K, nrow0,       0, tid, rB0);
  loadB(B, K, nrow0 + 128, 0, tid, rB1);
  writeB(sB + 0 * 8192, tid, rB0);
  writeB(sB + 1 * 8192, tid, rB1);
  if (NT > 1) {
    loadB(B, K, nrow0,       64, tid, rB0);
    loadB(B, K, nrow0 + 128, 64, tid, rB1);
    asm volatile("s_waitcnt vmcnt(8) lgkmcnt(0)" ::: "memory");
  } else {
    asm volatile("s_waitcnt vmcnt(0) lgkmcnt(0)" ::: "memory");
  }
  __builtin_amdgcn_s_barrier();

  for (int t = 0; t < NT; ++t) {
    const int P = t & 1;
    const short* aB = sA + (P * 2 + wm) * 8192;
    const short* bB = sB + (P * 2 + (wn >> 1)) * 8192;
    short* nxA = sA + ((P ^ 1) * 2) * 8192;
    short* nxB = sB + ((P ^ 1) * 2) * 8192;
    const int bcol = (wn & 1) * 64;

    // ---- phase a: ds_read A0 + B01; stage A0(t+1); lgkm throttle; MFMA q(0,0)
    #pragma unroll
    for (int mi = 0; mi < 4; ++mi) {
      a_[mi][0] = *(const bf16x8*)&aB[(mi * 16 + lr) * 64 + koff0];
      a_[mi][1] = *(const bf16x8*)&aB[(mi * 16 + lr) * 64 + koff1];
    }
    #pragma unroll
    for (int nj = 0; nj < 2; ++nj) {
      const int cb = (bcol + nj * 16 + lr) * 64;
      b_[nj][0] = *(const bf16x8*)&bB[cb + koff0];
      b_[nj][1] = *(const bf16x8*)&bB[cb + koff1];
    }
    if (t + 1 < NT) stage2(A, K, mrow0, (t + 1) * 64, nxA, tid);
    asm volatile("s_waitcnt lgkmcnt(8)" ::: "memory");  // throttle 12 ds_reads
    __builtin_amdgcn_s_barrier();
    MFMA16(0, 0)
    __builtin_amdgcn_s_barrier();

    // ---- phase b: ds_read B23; stage A1(t+1); MFMA quad(0,2)
    #pragma unroll
    for (int nj = 0; nj < 2; ++nj) {
      const int cb = (bcol + (nj + 2) * 16 + lr) * 64;
      b_[nj + 2][0] = *(const bf16x8*)&bB[cb + koff0];
      b_[nj + 2][1] = *(const bf16x8*)&bB[cb + koff1];
    }
    if (t + 1 < NT) stage2(A, K, mrow0 + 128, (t + 1) * 64, nxA + 8192, tid);
    __builtin_amdgcn_s_barrier();
    MFMA16(0, 2)
    __builtin_amdgcn_s_barrier();

    // ---- phase c: ds_read A1; writeB(t+1)h0; loadB(t+2)h0; MFMA quad(4,2)
    #pragma unroll
    for (int mi = 0; mi < 4; ++mi) {
      a_[mi][0] = *(const bf16x8*)&aB[(64 + mi * 16 + lr) * 64 + koff0];
      a_[mi][1] = *(const bf16x8*)&aB[(64 + mi * 16 + lr) * 64 + koff1];
    }
    if (t + 1 < NT) writeB(nxB, tid, rB0);
    if (t + 2 < NT) loadB(B, K, nrow0, (t + 2) * 64, tid, rB0);
    __builtin_amdgcn_s_barrier();
    MFMA16(4, 2)
    __builtin_amdgcn_s_barrier();

    // ---- phase d: writeB(t+1)h1; loadB(t+2)h1; MFMA quad(4,0); boundary
    if (t + 1 < NT) writeB(nxB + 8192, tid, rB1);
    if (t + 2 < NT) loadB(B, K, nrow0 + 128, (t + 2) * 64, tid, rB1);
    __builtin_amdgcn_s_barrier();
    MFMA16(4, 0)
    if (t + 2 < NT) asm volatile("s_waitcnt vmcnt(8) lgkmcnt(0)" ::: "memory");
    else            asm volatile("s_waitcnt vmcnt(0) lgkmcnt(0)" ::: "memory");
    __builtin_amdgcn_s_barrier();
  }

  // ---- epilogue: C/D layout col=lane&15, row=(lane>>4)*4+r; bf16 store
  #pragma unroll
  for (int im = 0; im < 8; ++im) {
    const int row = mrow0 + wm * 128 + im * 16 + ((lane >> 4) << 2);
    #pragma unroll
    for (int ni = 0; ni < 4; ++ni) {
      const int col = nrow0 + wn * 64 + ni * 16 + lr;
      #pragma unroll
      for (int rr = 0; rr < 4; ++rr)
        C[(size_t)(row + rr) * N + col] = bf16_rnd(acc[im][ni][rr]);
    }
  }
}

// ---------------- 128x128 fallback GEMM (fp32 in, reg-staged bf16) -----------
__global__ __launch_bounds__(256) void gemm_lean(const float* __restrict__ A,
                                                 const float* __restrict__ B,
                                                 unsigned short* __restrict__ C,
                                                 int N, int K) {
  __shared__ __align__(16) short sA[128 * 64];
  __shared__ __align__(16) short sB[128 * 64];
  const int t = threadIdx.x;
  const int lane = t & 63;
  const int wv = t >> 6;
  const int wm = wv >> 1, wn = wv & 1;
  const int rowA0 = blockIdx.x * 128;
  const int rowB0 = blockIdx.y * 128;

  f32x4 acc[4][4] = {};

  for (int k0 = 0; k0 < K; k0 += 64) {
    #pragma unroll
    for (int i = 0; i < 8; ++i) {
      const int o = i * 1024 + t * 4;
      const int row = o >> 6;
      const int kcol = o & 63;
      const int dst = row * 64 + (kcol ^ ((row & 7) << 3));
      float4 va = *(const float4*)(A + (size_t)(rowA0 + row) * K + k0 + kcol);
      float4 vb = *(const float4*)(B + (size_t)(rowB0 + row) * K + k0 + kcol);
      uint2 pa, pb;
      pa.x = pack_bf16_2(va.x, va.y); pa.y = pack_bf16_2(va.z, va.w);
      pb.x = pack_bf16_2(vb.x, vb.y); pb.y = pack_bf16_2(vb.z, vb.w);
      *(uint2*)(sA + dst) = pa;
      *(uint2*)(sB + dst) = pb;
    }
    __syncthreads();
    #pragma unroll
    for (int kk = 0; kk < 2; ++kk) {
      bf16x8 af[4], bfr[4];
      #pragma unroll
      for (int mi = 0; mi < 4; ++mi) {
        const int row = wm * 64 + mi * 16 + (lane & 15);
        const int koff = (kk * 32 + (lane >> 4) * 8) ^ ((row & 7) << 3);
        af[mi] = *(const bf16x8*)&sA[row * 64 + koff];
      }
      #pragma unroll
      for (int ni = 0; ni < 4; ++ni) {
        const int col = wn * 64 + ni * 16 + (lane & 15);
        const int koff = (kk * 32 + (lane >> 4) * 8) ^ ((col & 7) << 3);
        bfr[ni] = *(const bf16x8*)&sB[col * 64 + koff];
      }
      #pragma unroll
      for (int mi = 0; mi < 4; ++mi)
        #pragma unroll
        for (int ni = 0; ni < 4; ++ni)
          acc[mi][ni] = __builtin_amdgcn_mfma_f32_16x16x32_bf16(af[mi], bfr[ni],
                                                                acc[mi][ni], 0, 0, 0);
    }
    __syncthreads();
  }

  #pragma unroll
  for (int mi = 0; mi < 4; ++mi)
    #pragma unroll
    for (int ni = 0; ni < 4; ++ni) {
      const int col = rowB0 + wn * 64 + ni * 16 + (lane & 15);
      const int rowb = rowA0 + wm * 64 + mi * 16 + ((lane >> 4) * 4);
      #pragma unroll
      for (int r = 0; r < 4; ++r)
        C[(size_t)(rowb + r) * N + col] = bf16_rnd(acc[mi][ni][r]);
    }
}

// ---------------- fused lse + JSD + NLL: one block per row, rows in LDS ------
__global__ __launch_bounds__(1024) void fused_loss(const unsigned short* __restrict__ SL,
                                                   const unsigned short* __restrict__ TL,
                                                   int V,
                                                   const int* __restrict__ labels,
                                                   int rowOff, float* __restrict__ acc) {
  __shared__ __align__(16) unsigned short bufS[32768];
  __shared__ __align__(16) unsigned short bufT[32768];
  __shared__ float red[4][16];
  const int row = blockIdx.x;
  const int tid = threadIdx.x;
  const u16x8* ps = (const u16x8*)(SL + (size_t)row * V);
  const u16x8* pt = (const u16x8*)(TL + (size_t)row * V);
  const int n8 = V >> 3;

  float ms = -1e30f, ss = 0.f, mt = -1e30f, st = 0.f;
  for (int i = tid; i < n8; i += 1024) {
    u16x8 a = ps[i], b = pt[i];
    *(u16x8*)&bufS[i * 8] = a;
    *(u16x8*)&bufT[i * 8] = b;
    float lmS = -1e30f, lmT = -1e30f;
    float fa[8], fb[8];
    #pragma unroll
    for (int j = 0; j < 8; ++j) {
      fa[j] = bf16_f(a[j]); fb[j] = bf16_f(b[j]);
      lmS = fmaxf(lmS, fa[j]); lmT = fmaxf(lmT, fb[j]);
    }
    if (lmS > ms) { ss *= __expf(ms - lmS); ms = lmS; }
    if (lmT > mt) { st *= __expf(mt - lmT); mt = lmT; }
    #pragma unroll
    for (int j = 0; j < 8; ++j) {
      ss += __expf(fa[j] - ms);
      st += __expf(fb[j] - mt);
    }
  }
  #pragma unroll
  for (int off = 32; off > 0; off >>= 1) {
    float mo = __shfl_xor(ms, off), so = __shfl_xor(ss, off);
    float mn = fmaxf(ms, mo);
    ss = ss * __expf(ms - mn) + so * __expf(mo - mn); ms = mn;
    mo = __shfl_xor(mt, off); so = __shfl_xor(st, off);
    mn = fmaxf(mt, mo);
    st = st * __expf(mt - mn) + so * __expf(mo - mn); mt = mn;
  }
  const int w = tid >> 6;
  if ((tid & 63) == 0) { red[0][w] = ms; red[1][w] = ss; red[2][w] = mt; red[3][w] = st; }
  __syncthreads();
  __shared__ float lse2[2];
  if (tid == 0) {
    float M = red[0][0], S = red[1][0];
    for (int i = 1; i < 16; ++i) {
      float mn = fmaxf(M, red[0][i]);
      S = S * __expf(M - mn) + red[1][i] * __expf(red[0][i] - mn); M = mn;
    }
    lse2[0] = M + __logf(S);
    M = red[2][0]; S = red[3][0];
    for (int i = 1; i < 16; ++i) {
      float mn = fmaxf(M, red[2][i]);
      S = S * __expf(M - mn) + red[3][i] * __expf(red[2][i] - mn); M = mn;
    }
    lse2[1] = M + __logf(S);
  }
  __syncthreads();
  const float slse = lse2[0], tlse = lse2[1];
  const int lbl = labels[rowOff + row];

  float jsd = 0.f, hard = 0.f;
  for (int i = tid; i < n8; i += 1024) {
    u16x8 a = *(const u16x8*)&bufS[i * 8];
    u16x8 b = *(const u16x8*)&bufT[i * 8];
    #pragma unroll
    for (int j = 0; j < 8; ++j) {
      float sl = bf16_f(a[j]) - slse;
      float tl = bf16_f(b[j]) - tlse;
      float sp = __expf(sl), tp = __expf(tl);
      float lm = __logf(0.5f * (sp + tp));
      jsd += 0.5f * (tp * (tl - lm) + sp * (sl - lm));
      if (i * 8 + j == lbl) hard = -sl;
    }
  }
  #pragma unroll
  for (int off = 32; off > 0; off >>= 1) {
    jsd += __shfl_xor(jsd, off);
    hard += __shfl_xor(hard, off);
  }
  if ((tid & 63) == 0) { red[0][w] = jsd; red[1][w] = hard; }
  __syncthreads();
  if (tid == 0) {
    float J = 0.f, H = 0.f;
    for (int i = 0; i < 16; ++i) { J += red[0][i]; H += red[1][i]; }
    atomicAdd(&acc[0], H);
    atomicAdd(&acc[1], J);
  }
}

__global__ void finalize_loss(const float* __restrict__ acc, float* __restrict__ out,
                              float invn) {
  out[0] = 0.5f * acc[0] * invn + 0.5f * acc[1] * invn;
}

// -----------------------------------------------------------------------------
extern "C" void kernel_launch(void* const* d_in, const int* in_sizes, int n_in,
                              void* d_out, int out_size, void* d_ws, size_t ws_size,
                              hipStream_t stream) {
  const float* sIn = (const float*)d_in[0];
  const float* sW  = (const float*)d_in[1];
  const float* tIn = (const float*)d_in[2];
  const float* tW  = (const float*)d_in[3];
  const int*   lbl = (const int*)d_in[4];

  const int N  = in_sizes[4];          // 2048 tokens
  const int HS = in_sizes[0] / N;      // 2048
  const int HT = in_sizes[2] / N;      // 4096
  const int V  = in_sizes[1] / HS;     // 32000

  char* ws = (char*)d_ws;
  size_t off = 0;
  auto alloc = [&](size_t b) { size_t p = off; off = (off + b + 255) & ~(size_t)255; return p; };

  const size_t o_sInB = alloc((size_t)N * HS * 2);
  const size_t o_tInB = alloc((size_t)N * HT * 2);
  const size_t o_acc  = alloc(256);

  const bool shapeOK = (V % 256 == 0) && (V <= 32768) && (V % 8 == 0) &&
                       (HS % 64 == 0) && (HT % 64 == 0) && (N % 256 == 0);
  const size_t minLogits = 2ull * 256 * V * 2 + 512;
  const bool full = shapeOK && (off + minLogits) <= ws_size;

  size_t avail = ws_size > off ? ws_size - off : 0;
  int Rfit = (int)(avail / (2ull * V * 2));
  int R = full ? 256 : 128;
  while (R * 2 <= Rfit && R * 2 <= N) R *= 2;
  const size_t o_sL = alloc((size_t)R * V * 2);
  const size_t o_tL = alloc((size_t)R * V * 2);

  hipMemsetAsync(ws + o_acc, 0, 8, stream);

  if (full) {
    long long n4s = (long long)N * HS / 4;
    long long n4t = (long long)N * HT / 4;
    int grid = (int)(((n4s + n4t) + 255) / 256);
    if (grid > 2048) grid = 2048;
    cvt2_f32_bf16<<<grid, 256, 0, stream>>>(sIn, (uint2*)(ws + o_sInB), n4s,
                                            tIn, (uint2*)(ws + o_tInB), n4t);
  }

  const int Mt = R / 256;
  int mshift = 0;
  while ((1 << mshift) < Mt) ++mshift;

  for (int r0 = 0; r0 < N; r0 += R) {
    if (full) {
      const int half = Mt * (V / 256);
      gemm_dual<<<2 * half, 512, 0, stream>>>(
          (const short*)(ws + o_tInB + (size_t)r0 * HT * 2), tW,
          (unsigned short*)(ws + o_tL), HT, HT / 64,
          (const short*)(ws + o_sInB + (size_t)r0 * HS * 2), sW,
          (unsigned short*)(ws + o_sL), HS, HS / 64,
          V, mshift, half);
    } else {
      dim3 g(R / 128, V / 128);
      gemm_lean<<<g, 256, 0, stream>>>(sIn + (size_t)r0 * HS, sW,
                                       (unsigned short*)(ws + o_sL), V, HS);
      gemm_lean<<<g, 256, 0, stream>>>(tIn + (size_t)r0 * HT, tW,
                                       (unsigned short*)(ws + o_tL), V, HT);
    }
    fused_loss<<<R, 1024, 0, stream>>>((const unsigned short*)(ws + o_sL),
                                       (const unsigned short*)(ws + o_tL), V,
                                       lbl, r0, (float*)(ws + o_acc));
  }

  finalize_loss<<<1, 1, 0, stream>>>((float*)(ws + o_acc), (float*)d_out, 1.0f / N);
}

// Round 10
// 1019.675 us; speedup vs baseline: 1.2650x; 1.2650x over previous
//
#include <hip/hip_runtime.h>
#include <stdint.h>

#define AS1C(p) ((const __attribute__((address_space(1))) void*)(p))
#define AS3(p)  ((__attribute__((address_space(3))) void*)(p))

typedef short bf16x8 __attribute__((ext_vector_type(8)));
typedef float f32x4  __attribute__((ext_vector_type(4)));
typedef unsigned short u16x8 __attribute__((ext_vector_type(8)));

static __device__ __forceinline__ unsigned pack_bf16_2(float lo, float hi) {
  return (__float_as_uint(lo) >> 16) | (__float_as_uint(hi) & 0xFFFF0000u);
}
static __device__ __forceinline__ unsigned short bf16_rnd(float v) {
  return (unsigned short)((__float_as_uint(v) + 0x8000u) >> 16);
}
static __device__ __forceinline__ float bf16_f(unsigned short u) {
  return __uint_as_float(((unsigned)u) << 16);
}

// ---------------- fp32 -> bf16 convert, both inputs in one launch ------------
__global__ __launch_bounds__(256) void cvt2_f32_bf16(const float* __restrict__ inS,
                                                     uint2* __restrict__ outS,
                                                     long long n4s,
                                                     const float* __restrict__ inT,
                                                     uint2* __restrict__ outT,
                                                     long long n4t) {
  long long i = (long long)blockIdx.x * blockDim.x + threadIdx.x;
  long long stride = (long long)gridDim.x * blockDim.x;
  const long long tot = n4s + n4t;
  for (; i < tot; i += stride) {
    const float4* src; uint2* dst; long long j;
    if (i < n4s) { src = (const float4*)inS; dst = outS; j = i; }
    else         { src = (const float4*)inT; dst = outT; j = i - n4s; }
    float4 v = src[j];
    uint2 o;
    o.x = pack_bf16_2(v.x, v.y);
    o.y = pack_bf16_2(v.z, v.w);
    dst[j] = o;
  }
}

// ---------------- 256x256 8-phase GEMM (R5 schedule), DUAL dispatch ----------
// R8-exact (best measured: 1022 us total). Sequential halves: teacher blocks
// [0, halfGrid) first, student backfills — each XCD's L2 holds ONE weight
// matrix's panels at a time (R9's interleave broke this: FETCH +31%).
//   phase a: ds_read A0+B01; stage2 A0(t+1)              | MFMA quad(0,0)
//   phase b: ds_read B23;    stage2 A1(t+1)              | MFMA quad(0,2)
//   phase c: ds_read A1;     writeB(t+1)h0; loadB(t+2)h0 | MFMA quad(4,2)
//   phase d:                 writeB(t+1)h1; loadB(t+2)h1 | MFMA quad(4,0)
//   boundary: s_waitcnt vmcnt(8) lgkmcnt(0)  (8 B-f4s stay in flight)

static __device__ __forceinline__ void stage2(const short* __restrict__ G, int K,
                                              int grow0, int k0,
                                              short* lds, int tid) {
  const int rl = tid >> 3;
  const int ks = ((tid & 7) ^ (rl & 7)) << 3;    // pre-swizzled source k
  const short* src = G + (size_t)(grow0 + rl) * K + k0 + ks;
  short* dst = lds + (tid >> 6) * 512;
  __builtin_amdgcn_global_load_lds(AS1C(src), AS3(dst), 16, 0, 0);
  __builtin_amdgcn_global_load_lds(AS1C(src + (size_t)64 * K), AS3(dst + 4096), 16, 0, 0);
}

static __device__ __forceinline__ void loadB(const float* __restrict__ B, int K,
                                             int grow0, int k0, int tid, float4* r) {
  const int row = tid >> 2;
  const int kb = (tid & 3) << 4;
  const float* s = B + (size_t)(grow0 + row) * K + k0 + kb;
  r[0] = *(const float4*)(s);
  r[1] = *(const float4*)(s + 4);
  r[2] = *(const float4*)(s + 8);
  r[3] = *(const float4*)(s + 12);
}

static __device__ __forceinline__ void writeB(short* buf, int tid, const float4* r) {
  const int row = tid >> 2;
  const int g0 = (tid & 3) << 1;
  uint4 w0, w1;
  w0.x = pack_bf16_2(r[0].x, r[0].y); w0.y = pack_bf16_2(r[0].z, r[0].w);
  w0.z = pack_bf16_2(r[1].x, r[1].y); w0.w = pack_bf16_2(r[1].z, r[1].w);
  w1.x = pack_bf16_2(r[2].x, r[2].y); w1.y = pack_bf16_2(r[2].z, r[2].w);
  w1.z = pack_bf16_2(r[3].x, r[3].y); w1.w = pack_bf16_2(r[3].z, r[3].w);
  const int x = (row & 7) << 3;
  *(uint4*)(buf + row * 64 + ((g0 * 8) ^ x))       = w0;
  *(uint4*)(buf + row * 64 + (((g0 + 1) * 8) ^ x)) = w1;
}

#define MFMA16(IM0, JN0)                                                        \
  __builtin_amdgcn_s_setprio(1);                                                \
  _Pragma("unroll")                                                             \
  for (int mi = 0; mi < 4; ++mi) {                                              \
    _Pragma("unroll")                                                           \
    for (int nj = 0; nj < 2; ++nj) {                                            \
      acc[(IM0) + mi][(JN0) + nj] = __builtin_amdgcn_mfma_f32_16x16x32_bf16(    \
          a_[mi][0], b_[(JN0) + nj][0], acc[(IM0) + mi][(JN0) + nj], 0, 0, 0);  \
      acc[(IM0) + mi][(JN0) + nj] = __builtin_amdgcn_mfma_f32_16x16x32_bf16(    \
          a_[mi][1], b_[(JN0) + nj][1], acc[(IM0) + mi][(JN0) + nj], 0, 0, 0);  \
    }                                                                           \
  }                                                                             \
  __builtin_amdgcn_s_setprio(0);

__global__ __launch_bounds__(512, 2) void gemm_dual(
    const short* __restrict__ A0v, const float* __restrict__ B0v,
    unsigned short* __restrict__ C0v, int K0, int NT0,
    const short* __restrict__ A1v, const float* __restrict__ B1v,
    unsigned short* __restrict__ C1v, int K1, int NT1,
    int N, int mshift, int halfGrid) {
  __shared__ __align__(16) short sA[4 * 8192];
  __shared__ __align__(16) short sB[4 * 8192];

  const int tid = threadIdx.x;
  const int lane = tid & 63;
  const int wv = tid >> 6;
  const int wm = wv >> 2;
  const int wn = wv & 3;

  // select job (block-uniform): sequential halves (teacher first)
  const bool second = (int)blockIdx.x >= halfGrid;
  const short* A = second ? A1v : A0v;
  const float* B = second ? B1v : B0v;
  unsigned short* C = second ? C1v : C0v;
  const int K  = second ? K1  : K0;
  const int NT = second ? NT1 : NT0;
  const int orig = (int)blockIdx.x - (second ? halfGrid : 0);

  // bijective XCD-aware swizzle within each half (nwg = halfGrid)
  const int nwg = halfGrid;
  const int q = nwg >> 3, r = nwg & 7;
  const int xcd = orig & 7;
  const int wg = (xcd < r ? xcd * (q + 1) : r * (q + 1) + (xcd - r) * q) + (orig >> 3);
  const int bm = wg & ((1 << mshift) - 1);
  const int bn = wg >> mshift;

  const int mrow0 = bm << 8;
  const int nrow0 = bn << 8;

  const int lr = lane & 15;
  const int koff0 = (((lane >> 4) << 3) ^ ((lane & 7) << 3));
  const int koff1 = ((32 + ((lane >> 4) << 3)) ^ ((lane & 7) << 3));

  f32x4 acc[8][4] = {};
  bf16x8 a_[4][2], b_[4][2];
  float4 rB0[4], rB1[4];

  // ---- prologue: A(0) glds; B(0) regs->LDS; B(1) -> regs (8 f4 in flight)
  stage2(A, K, mrow0,       0, sA + 0 * 8192, tid);
  stage2(A, K, mrow0 + 128, 0, sA + 1 * 8192, tid);
  loadB(B, K, nrow0,       0, tid, rB0);
  loadB(B, K, nrow0 + 128, 0, tid, rB1);
  writeB(sB + 0 * 8192, tid, rB0);
  writeB(sB + 1 * 8192, tid, rB1);
  if (NT > 1) {
    loadB(B, K, nrow0,       64, tid, rB0);
    loadB(B, K, nrow0 + 128, 64, tid, rB1);
    asm volatile("s_waitcnt vmcnt(8) lgkmcnt(0)" ::: "memory");
  } else {
    asm volatile("s_waitcnt vmcnt(0) lgkmcnt(0)" ::: "memory");
  }
  __builtin_amdgcn_s_barrier();

  for (int t = 0; t < NT; ++t) {
    const int P = t & 1;
    const short* aB = sA + (P * 2 + wm) * 8192;
    const short* bB = sB + (P * 2 + (wn >> 1)) * 8192;
    short* nxA = sA + ((P ^ 1) * 2) * 8192;
    short* nxB = sB + ((P ^ 1) * 2) * 8192;
    const int bcol = (wn & 1) * 64;

    // ---- phase a: ds_read A0 + B01; stage A0(t+1); MFMA quad(0,0)
    #pragma unroll
    for (int mi = 0; mi < 4; ++mi) {
      a_[mi][0] = *(const bf16x8*)&aB[(mi * 16 + lr) * 64 + koff0];
      a_[mi][1] = *(const bf16x8*)&aB[(mi * 16 + lr) * 64 + koff1];
    }
    #pragma unroll
    for (int nj = 0; nj < 2; ++nj) {
      const int cb = (bcol + nj * 16 + lr) * 64;
      b_[nj][0] = *(const bf16x8*)&bB[cb + koff0];
      b_[nj][1] = *(const bf16x8*)&bB[cb + koff1];
    }
    if (t + 1 < NT) stage2(A, K, mrow0, (t + 1) * 64, nxA, tid);
    __builtin_amdgcn_s_barrier();
    MFMA16(0, 0)
    __builtin_amdgcn_s_barrier();

    // ---- phase b: ds_read B23; stage A1(t+1); MFMA quad(0,2)
    #pragma unroll
    for (int nj = 0; nj < 2; ++nj) {
      const int cb = (bcol + (nj + 2) * 16 + lr) * 64;
      b_[nj + 2][0] = *(const bf16x8*)&bB[cb + koff0];
      b_[nj + 2][1] = *(const bf16x8*)&bB[cb + koff1];
    }
    if (t + 1 < NT) stage2(A, K, mrow0 + 128, (t + 1) * 64, nxA + 8192, tid);
    __builtin_amdgcn_s_barrier();
    MFMA16(0, 2)
    __builtin_amdgcn_s_barrier();

    // ---- phase c: ds_read A1; writeB(t+1)h0; loadB(t+2)h0; MFMA quad(4,2)
    #pragma unroll
    for (int mi = 0; mi < 4; ++mi) {
      a_[mi][0] = *(const bf16x8*)&aB[(64 + mi * 16 + lr) * 64 + koff0];
      a_[mi][1] = *(const bf16x8*)&aB[(64 + mi * 16 + lr) * 64 + koff1];
    }
    if (t + 1 < NT) writeB(nxB, tid, rB0);
    if (t + 2 < NT) loadB(B, K, nrow0, (t + 2) * 64, tid, rB0);
    __builtin_amdgcn_s_barrier();
    MFMA16(4, 2)
    __builtin_amdgcn_s_barrier();

    // ---- phase d: writeB(t+1)h1; loadB(t+2)h1; MFMA quad(4,0); boundary
    if (t + 1 < NT) writeB(nxB + 8192, tid, rB1);
    if (t + 2 < NT) loadB(B, K, nrow0 + 128, (t + 2) * 64, tid, rB1);
    __builtin_amdgcn_s_barrier();
    MFMA16(4, 0)
    if (t + 2 < NT) asm volatile("s_waitcnt vmcnt(8) lgkmcnt(0)" ::: "memory");
    else            asm volatile("s_waitcnt vmcnt(0) lgkmcnt(0)" ::: "memory");
    __builtin_amdgcn_s_barrier();
  }

  // ---- epilogue: C/D layout col=lane&15, row=(lane>>4)*4+r; bf16 store
  #pragma unroll
  for (int im = 0; im < 8; ++im) {
    const int row = mrow0 + wm * 128 + im * 16 + ((lane >> 4) << 2);
    #pragma unroll
    for (int ni = 0; ni < 4; ++ni) {
      const int col = nrow0 + wn * 64 + ni * 16 + lr;
      #pragma unroll
      for (int rr = 0; rr < 4; ++rr)
        C[(size_t)(row + rr) * N + col] = bf16_rnd(acc[im][ni][rr]);
    }
  }
}

// ---------------- 128x128 fallback GEMM (fp32 in, reg-staged bf16) -----------
__global__ __launch_bounds__(256) void gemm_lean(const float* __restrict__ A,
                                                 const float* __restrict__ B,
                                                 unsigned short* __restrict__ C,
                                                 int N, int K) {
  __shared__ __align__(16) short sA[128 * 64];
  __shared__ __align__(16) short sB[128 * 64];
  const int t = threadIdx.x;
  const int lane = t & 63;
  const int wv = t >> 6;
  const int wm = wv >> 1, wn = wv & 1;
  const int rowA0 = blockIdx.x * 128;
  const int rowB0 = blockIdx.y * 128;

  f32x4 acc[4][4] = {};

  for (int k0 = 0; k0 < K; k0 += 64) {
    #pragma unroll
    for (int i = 0; i < 8; ++i) {
      const int o = i * 1024 + t * 4;
      const int row = o >> 6;
      const int kcol = o & 63;
      const int dst = row * 64 + (kcol ^ ((row & 7) << 3));
      float4 va = *(const float4*)(A + (size_t)(rowA0 + row) * K + k0 + kcol);
      float4 vb = *(const float4*)(B + (size_t)(rowB0 + row) * K + k0 + kcol);
      uint2 pa, pb;
      pa.x = pack_bf16_2(va.x, va.y); pa.y = pack_bf16_2(va.z, va.w);
      pb.x = pack_bf16_2(vb.x, vb.y); pb.y = pack_bf16_2(vb.z, vb.w);
      *(uint2*)(sA + dst) = pa;
      *(uint2*)(sB + dst) = pb;
    }
    __syncthreads();
    #pragma unroll
    for (int kk = 0; kk < 2; ++kk) {
      bf16x8 af[4], bfr[4];
      #pragma unroll
      for (int mi = 0; mi < 4; ++mi) {
        const int row = wm * 64 + mi * 16 + (lane & 15);
        const int koff = (kk * 32 + (lane >> 4) * 8) ^ ((row & 7) << 3);
        af[mi] = *(const bf16x8*)&sA[row * 64 + koff];
      }
      #pragma unroll
      for (int ni = 0; ni < 4; ++ni) {
        const int col = wn * 64 + ni * 16 + (lane & 15);
        const int koff = (kk * 32 + (lane >> 4) * 8) ^ ((col & 7) << 3);
        bfr[ni] = *(const bf16x8*)&sB[col * 64 + koff];
      }
      #pragma unroll
      for (int mi = 0; mi < 4; ++mi)
        #pragma unroll
        for (int ni = 0; ni < 4; ++ni)
          acc[mi][ni] = __builtin_amdgcn_mfma_f32_16x16x32_bf16(af[mi], bfr[ni],
                                                                acc[mi][ni], 0, 0, 0);
    }
    __syncthreads();
  }

  #pragma unroll
  for (int mi = 0; mi < 4; ++mi)
    #pragma unroll
    for (int ni = 0; ni < 4; ++ni) {
      const int col = rowB0 + wn * 64 + ni * 16 + (lane & 15);
      const int rowb = rowA0 + wm * 64 + mi * 16 + ((lane >> 4) * 4);
      #pragma unroll
      for (int r = 0; r < 4; ++r)
        C[(size_t)(rowb + r) * N + col] = bf16_rnd(acc[mi][ni][r]);
    }
}

// ---------------- fused lse + JSD + NLL: one block per row, rows in LDS ------
__global__ __launch_bounds__(1024) void fused_loss(const unsigned short* __restrict__ SL,
                                                   const unsigned short* __restrict__ TL,
                                                   int V,
                                                   const int* __restrict__ labels,
                                                   int rowOff, float* __restrict__ acc) {
  __shared__ __align__(16) unsigned short bufS[32768];
  __shared__ __align__(16) unsigned short bufT[32768];
  __shared__ float red[4][16];
  const int row = blockIdx.x;
  const int tid = threadIdx.x;
  const u16x8* ps = (const u16x8*)(SL + (size_t)row * V);
  const u16x8* pt = (const u16x8*)(TL + (size_t)row * V);
  const int n8 = V >> 3;

  float ms = -1e30f, ss = 0.f, mt = -1e30f, st = 0.f;
  for (int i = tid; i < n8; i += 1024) {
    u16x8 a = ps[i], b = pt[i];
    *(u16x8*)&bufS[i * 8] = a;
    *(u16x8*)&bufT[i * 8] = b;
    float lmS = -1e30f, lmT = -1e30f;
    float fa[8], fb[8];
    #pragma unroll
    for (int j = 0; j < 8; ++j) {
      fa[j] = bf16_f(a[j]); fb[j] = bf16_f(b[j]);
      lmS = fmaxf(lmS, fa[j]); lmT = fmaxf(lmT, fb[j]);
    }
    if (lmS > ms) { ss *= __expf(ms - lmS); ms = lmS; }
    if (lmT > mt) { st *= __expf(mt - lmT); mt = lmT; }
    #pragma unroll
    for (int j = 0; j < 8; ++j) {
      ss += __expf(fa[j] - ms);
      st += __expf(fb[j] - mt);
    }
  }
  #pragma unroll
  for (int off = 32; off > 0; off >>= 1) {
    float mo = __shfl_xor(ms, off), so = __shfl_xor(ss, off);
    float mn = fmaxf(ms, mo);
    ss = ss * __expf(ms - mn) + so * __expf(mo - mn); ms = mn;
    mo = __shfl_xor(mt, off); so = __shfl_xor(st, off);
    mn = fmaxf(mt, mo);
    st = st * __expf(mt - mn) + so * __expf(mo - mn); mt = mn;
  }
  const int w = tid >> 6;
  if ((tid & 63) == 0) { red[0][w] = ms; red[1][w] = ss; red[2][w] = mt; red[3][w] = st; }
  __syncthreads();
  __shared__ float lse2[2];
  if (tid == 0) {
    float M = red[0][0], S = red[1][0];
    for (int i = 1; i < 16; ++i) {
      float mn = fmaxf(M, red[0][i]);
      S = S * __expf(M - mn) + red[1][i] * __expf(red[0][i] - mn); M = mn;
    }
    lse2[0] = M + __logf(S);
    M = red[2][0]; S = red[3][0];
    for (int i = 1; i < 16; ++i) {
      float mn = fmaxf(M, red[2][i]);
      S = S * __expf(M - mn) + red[3][i] * __expf(red[2][i] - mn); M = mn;
    }
    lse2[1] = M + __logf(S);
  }
  __syncthreads();
  const float slse = lse2[0], tlse = lse2[1];
  const int lbl = labels[rowOff + row];

  float jsd = 0.f, hard = 0.f;
  for (int i = tid; i < n8; i += 1024) {
    u16x8 a = *(const u16x8*)&bufS[i * 8];
    u16x8 b = *(const u16x8*)&bufT[i * 8];
    #pragma unroll
    for (int j = 0; j < 8; ++j) {
      float sl = bf16_f(a[j]) - slse;
      float tl = bf16_f(b[j]) - tlse;
      float sp = __expf(sl), tp = __expf(tl);
      float lm = __logf(0.5f * (sp + tp));
      jsd += 0.5f * (tp * (tl - lm) + sp * (sl - lm));
      if (i * 8 + j == lbl) hard = -sl;
    }
  }
  #pragma unroll
  for (int off = 32; off > 0; off >>= 1) {
    jsd += __shfl_xor(jsd, off);
    hard += __shfl_xor(hard, off);
  }
  if ((tid & 63) == 0) { red[0][w] = jsd; red[1][w] = hard; }
  __syncthreads();
  if (tid == 0) {
    float J = 0.f, H = 0.f;
    for (int i = 0; i < 16; ++i) { J += red[0][i]; H += red[1][i]; }
    atomicAdd(&acc[0], H);
    atomicAdd(&acc[1], J);
  }
}

__global__ void finalize_loss(const float* __restrict__ acc, float* __restrict__ out,
                              float invn) {
  out[0] = 0.5f * acc[0] * invn + 0.5f * acc[1] * invn;
}

// -----------------------------------------------------------------------------
extern "C" void kernel_launch(void* const* d_in, const int* in_sizes, int n_in,
                              void* d_out, int out_size, void* d_ws, size_t ws_size,
                              hipStream_t stream) {
  const float* sIn = (const float*)d_in[0];
  const float* sW  = (const float*)d_in[1];
  const float* tIn = (const float*)d_in[2];
  const float* tW  = (const float*)d_in[3];
  const int*   lbl = (const int*)d_in[4];

  const int N  = in_sizes[4];          // 2048 tokens
  const int HS = in_sizes[0] / N;      // 2048
  const int HT = in_sizes[2] / N;      // 4096
  const int V  = in_sizes[1] / HS;     // 32000

  char* ws = (char*)d_ws;
  size_t off = 0;
  auto alloc = [&](size_t b) { size_t p = off; off = (off + b + 255) & ~(size_t)255; return p; };

  const size_t o_sInB = alloc((size_t)N * HS * 2);
  const size_t o_tInB = alloc((size_t)N * HT * 2);
  const size_t o_acc  = alloc(256);

  const bool shapeOK = (V % 256 == 0) && (V <= 32768) && (V % 8 == 0) &&
                       (HS % 64 == 0) && (HT % 64 == 0) && (N % 256 == 0);
  const size_t minLogits = 2ull * 256 * V * 2 + 512;
  const bool full = shapeOK && (off + minLogits) <= ws_size;

  size_t avail = ws_size > off ? ws_size - off : 0;
  int Rfit = (int)(avail / (2ull * V * 2));
  int R = full ? 256 : 128;
  while (R * 2 <= Rfit && R * 2 <= N) R *= 2;
  const size_t o_sL = alloc((size_t)R * V * 2);
  const size_t o_tL = alloc((size_t)R * V * 2);

  hipMemsetAsync(ws + o_acc, 0, 8, stream);

  if (full) {
    long long n4s = (long long)N * HS / 4;
    long long n4t = (long long)N * HT / 4;
    int grid = (int)(((n4s + n4t) + 255) / 256);
    if (grid > 2048) grid = 2048;
    cvt2_f32_bf16<<<grid, 256, 0, stream>>>(sIn, (uint2*)(ws + o_sInB), n4s,
                                            tIn, (uint2*)(ws + o_tInB), n4t);
  }

  const int Mt = R / 256;
  int mshift = 0;
  while ((1 << mshift) < Mt) ++mshift;

  for (int r0 = 0; r0 < N; r0 += R) {
    if (full) {
      const int half = Mt * (V / 256);
      // teacher first (longer job), student backfills as CUs free up
      gemm_dual<<<2 * half, 512, 0, stream>>>(
          (const short*)(ws + o_tInB + (size_t)r0 * HT * 2), tW,
          (unsigned short*)(ws + o_tL), HT, HT / 64,
          (const short*)(ws + o_sInB + (size_t)r0 * HS * 2), sW,
          (unsigned short*)(ws + o_sL), HS, HS / 64,
          V, mshift, half);
    } else {
      dim3 g(R / 128, V / 128);
      gemm_lean<<<g, 256, 0, stream>>>(sIn + (size_t)r0 * HS, sW,
                                       (unsigned short*)(ws + o_sL), V, HS);
      gemm_lean<<<g, 256, 0, stream>>>(tIn + (size_t)r0 * HT, tW,
                                       (unsigned short*)(ws + o_tL), V, HT);
    }
    fused_loss<<<R, 1024, 0, stream>>>((const unsigned short*)(ws + o_sL),
                                       (const unsigned short*)(ws + o_tL), V,
                                       lbl, r0, (float*)(ws + o_acc));
  }

  finalize_loss<<<1, 1, 0, stream>>>((float*)(ws + o_acc), (float*)d_out, 1.0f / N);
}